// Round 2
// baseline (233.741 us; speedup 1.0000x reference)
//
#include <hip/hip_runtime.h>
#include <stdint.h>

#define NBINS 32
#define NBATCH 64
#define NPB (512 * 512)            // pixels per batch
#define BPB 32                     // blocks per batch
#define TPB 256
#define ELEMS_PER_BLOCK (NPB / BPB)            // 8192
#define F4_PER_THREAD (ELEMS_PER_BLOCK / (TPB * 4))  // 8

// ws layout (uint32 words):
//   [0, 2048)      obs counts   [b*32 + j]
//   [2048, 4096)   pred counts  [b*32 + j]
//   [4096, 4160)   n_masked per batch
//   [4160]         mask-format flag: 1 => bytes (bool/u8), 0 => int32
#define WS_PRED 2048
#define WS_NM   4096
#define WS_FLAG 4160
#define WS_WORDS 4161

__global__ void detect_mask_kernel(const uint32_t* __restrict__ mw,
                                   uint32_t* __restrict__ flag) {
  uint32_t v = mw[blockIdx.x * blockDim.x + threadIdx.x];
  if (v > 1u) atomicOr(flag, 1u);
}

__device__ __forceinline__ void bucket_add(float x, bool m, const float* se,
                                           float e0, float eN, float invw,
                                           uint32_t* h) {
  if (!m) return;
  if (!(x >= e0 && x <= eN)) return;       // valid range check (NaN-safe)
  int i = (int)((x - e0) * invw);          // analytic guess (x>=e0 => t>=0)
  if (i > NBINS - 1) i = NBINS - 1;
  if (i < 0) i = 0;
  // exact searchsorted(side='right')-1 semantics vs the real edges:
  while (i > 0 && x < se[i]) --i;
  while (i < NBINS - 1 && x >= se[i + 1]) ++i;
  atomicAdd(&h[i], 1u);
}

__global__ __launch_bounds__(TPB) void hist_kernel(
    const float* __restrict__ obs, const float* __restrict__ pred,
    const void* __restrict__ mask, const float* __restrict__ edges,
    uint32_t* __restrict__ ws) {
  __shared__ uint32_t h_obs[NBINS];
  __shared__ uint32_t h_pred[NBINS];
  __shared__ float se[NBINS + 1];
  __shared__ uint32_t smask;

  const int tid = threadIdx.x;
  if (tid < NBINS) { h_obs[tid] = 0u; h_pred[tid] = 0u; }
  if (tid < NBINS + 1) se[tid] = edges[tid];
  if (tid == 0) smask = 0u;
  __syncthreads();

  const uint32_t is_u8 = ws[WS_FLAG];      // uniform branch flag
  const int b = blockIdx.x / BPB;
  const int chunk = blockIdx.x % BPB;
  const size_t base_f4 =
      (((size_t)b * NPB) + ((size_t)chunk * ELEMS_PER_BLOCK)) >> 2;

  const float4* __restrict__ o4 = (const float4*)obs;
  const float4* __restrict__ p4 = (const float4*)pred;
  const uint32_t* __restrict__ mw = (const uint32_t*)mask;
  const int4* __restrict__ mi = (const int4*)mask;

  const float e0 = se[0];
  const float eN = se[NBINS];
  const float invw = (float)NBINS / (eN - e0);
  uint32_t nm = 0;

#pragma unroll
  for (int it = 0; it < F4_PER_THREAD; ++it) {
    const size_t idx = base_f4 + (size_t)(it * TPB + tid);
    const float4 xo = o4[idx];
    const float4 xp = p4[idx];
    bool m0, m1, m2, m3;
    if (is_u8) {
      const uint32_t w = mw[idx];
      m0 = (w & 0x000000ffu) != 0u;
      m1 = (w & 0x0000ff00u) != 0u;
      m2 = (w & 0x00ff0000u) != 0u;
      m3 = (w & 0xff000000u) != 0u;
    } else {
      const int4 mv = mi[idx];
      m0 = mv.x != 0; m1 = mv.y != 0; m2 = mv.z != 0; m3 = mv.w != 0;
    }
    nm += (m0 ? 1u : 0u) + (m1 ? 1u : 0u) + (m2 ? 1u : 0u) + (m3 ? 1u : 0u);

    bucket_add(xo.x, m0, se, e0, eN, invw, h_obs);
    bucket_add(xo.y, m1, se, e0, eN, invw, h_obs);
    bucket_add(xo.z, m2, se, e0, eN, invw, h_obs);
    bucket_add(xo.w, m3, se, e0, eN, invw, h_obs);

    bucket_add(xp.x, m0, se, e0, eN, invw, h_pred);
    bucket_add(xp.y, m1, se, e0, eN, invw, h_pred);
    bucket_add(xp.z, m2, se, e0, eN, invw, h_pred);
    bucket_add(xp.w, m3, se, e0, eN, invw, h_pred);
  }

  atomicAdd(&smask, nm);
  __syncthreads();

  if (tid < NBINS) {
    const uint32_t ho = h_obs[tid];
    const uint32_t hp = h_pred[tid];
    if (ho) atomicAdd(&ws[b * NBINS + tid], ho);
    if (hp) atomicAdd(&ws[WS_PRED + b * NBINS + tid], hp);
  }
  if (tid == 0) atomicAdd(&ws[WS_NM + b], smask);
}

__global__ __launch_bounds__(64) void finalize_kernel(
    const uint32_t* __restrict__ ws, const float* __restrict__ edges,
    float* __restrict__ out) {
  __shared__ float pobs[NBATCH][NBINS + 1];   // +1 pad
  __shared__ float ppred[NBATCH][NBINS + 1];
  __shared__ float w_sh[NBINS];
  __shared__ float bw_sh[NBINS];
  __shared__ float w_scale;

  const int t = threadIdx.x;  // one batch per thread, 64 threads = 1 wave

  // --- per-batch proportions ---
  const uint32_t* co = ws + t * NBINS;
  const uint32_t* cp = ws + WS_PRED + t * NBINS;
  const uint32_t nmask = ws[WS_NM + t];

  float sum_o = 0.0f, sum_p = 0.0f;
#pragma unroll
  for (int j = 0; j < NBINS; ++j) {
    float vo = (nmask == 0u) ? 1.0f : (float)co[j];
    float vp = (nmask == 0u) ? 1.0f : (float)cp[j];
    pobs[t][j] = vo;  sum_o += vo;
    ppred[t][j] = vp; sum_p += vp;
  }
  const float inv_to = 1.0f / fmaxf(sum_o, 1.0f);
  const float inv_tp = 1.0f / fmaxf(sum_p, 1.0f);
#pragma unroll
  for (int j = 0; j < NBINS; ++j) {
    pobs[t][j] *= inv_to;
    ppred[t][j] = 0.95f * (ppred[t][j] * inv_tp) + 0.05f / (float)NBINS;
  }
  __syncthreads();

  // --- class-balance weights (avg over batches per bin) ---
  if (t < NBINS) {
    float s = 0.0f;
#pragma unroll
    for (int b = 0; b < NBATCH; ++b) s += pobs[b][t];
    const float avg = s / (float)NBATCH;
    w_sh[t] = 1.0f / (avg + 1e-3f);
    // bin widths from midpoints; bw[31] = bw[30]
    const int j2 = (t < NBINS - 1) ? t : (NBINS - 2);
    const float mA = 0.5f * (edges[j2] + edges[j2 + 1]);
    const float mB = 0.5f * (edges[j2 + 1] + edges[j2 + 2]);
    bw_sh[t] = mB - mA;
  }
  __syncthreads();
  if (t == 0) {
    float sw = 0.0f;
#pragma unroll
    for (int j = 0; j < NBINS; ++j) sw += w_sh[j];
    w_scale = (float)NBINS / sw;
  }
  __syncthreads();

  // --- per-batch CE and W2 ---
  float ce = 0.0f, w2 = 0.0f, cdf_o = 0.0f, cdf_p = 0.0f;
#pragma unroll
  for (int j = 0; j < NBINS; ++j) {
    const float po = pobs[t][j];
    const float pp = ppred[t][j];
    ce += -po * logf(pp + 1e-8f) * (w_sh[j] * w_scale);
    cdf_o += po;
    cdf_p += pp;
    const float d = cdf_o - cdf_p;
    w2 += d * d * bw_sh[j];
  }

  // mean over 64 batches via wave shuffle reduce
  float ce_r = ce, w2_r = w2;
#pragma unroll
  for (int off = 32; off >= 1; off >>= 1) {
    ce_r += __shfl_down(ce_r, off);
    w2_r += __shfl_down(w2_r, off);
  }
  if (t == 0) {
    const float ce_m = ce_r / (float)NBATCH;
    const float w2_m = w2_r / (float)NBATCH;
    out[0] = (ce_m + 0.1f * w2_m) / (float)NBINS;
    out[1] = ce_m;
    out[2] = w2_m;
  }

  // p_obs / p_pred outputs
#pragma unroll
  for (int j = 0; j < NBINS; ++j) {
    out[3 + t * NBINS + j] = pobs[t][j];
    out[3 + NBATCH * NBINS + t * NBINS + j] = ppred[t][j];
  }
}

extern "C" void kernel_launch(void* const* d_in, const int* in_sizes, int n_in,
                              void* d_out, int out_size, void* d_ws,
                              size_t ws_size, hipStream_t stream) {
  const float* obs = (const float*)d_in[0];
  const float* pred = (const float*)d_in[1];
  const void* mask = d_in[2];
  const float* edges = (const float*)d_in[3];
  float* out = (float*)d_out;
  uint32_t* ws = (uint32_t*)d_ws;

  hipMemsetAsync(d_ws, 0, WS_WORDS * sizeof(uint32_t), stream);
  // Detect mask element width: scan first 64KB as u32 words. Byte-packed
  // random 0/1 mask => words > 1 almost surely; int32 0/1 => words in {0,1}.
  detect_mask_kernel<<<64, 256, 0, stream>>>((const uint32_t*)mask,
                                             ws + WS_FLAG);
  hist_kernel<<<NBATCH * BPB, TPB, 0, stream>>>(obs, pred, mask, edges, ws);
  finalize_kernel<<<1, 64, 0, stream>>>(ws, edges, out);
}